// Round 10
// baseline (155.522 us; speedup 1.0000x reference)
//
#include <hip/hip_runtime.h>
#include <math.h>

namespace {
constexpr int B_ = 4096;
constexpr int C_ = 12288;
constexpr int NBIN = 64;
constexpr int CAP = 512;                 // per-bin slot capacity (mean 192, max ~260)
constexpr float DEG2RAD = 0.017453292519943295f;
constexpr float LOG2E = 1.4426950408889634f;
// w = exp(-2R*asin(s)/tau) = exp2(KN2*asin(s)), KN2 = -(2*6371/75)*log2(e)
constexpr float KN2 = -245.10427f;
// asin(s) ~= s*(1 + a/6), a = s^2; KN2*asin(s) = s*(C0 + C1*a)
constexpr float C0 = KN2;
constexpr float C1 = KN2 / 6.0f;
// Pairs beyond 1800 km contribute w/w_near < e^-16 rel -> invisible at thr 0.1975.
// dist <= 1800 km => |dlat| <= 16.2 deg -> lat-bin band is a superset. (absmax
// 0.0 validated in rounds 8 and 9.)
constexpr float BANDDEG = 16.2f;
constexpr float BINSCALE = 64.0f / 180.0f;
}

__device__ __forceinline__ float wave_red_add(float v) {
#pragma unroll
    for (int off = 32; off > 0; off >>= 1) v += __shfl_down(v, off, 64);
    return v;
}

// Blocks 0..15: wave-per-bin compaction (wave w of block bl owns bin bl*4+w).
// Pure ballot/popc scan, NO __syncthreads (round 9's setup cost ~25-30 us).
// Stable original order -> deterministic. Sentinel pads (0,0,0,col0): a=0.5
// -> w = 2^-188 -> 0 for every row.
// Blocks 16..31: per-row query vectors (-0.5*unit_xyz, lat_deg).
__global__ __launch_bounds__(256) void setup_kernel(
    const float* __restrict__ centroids, const float* __restrict__ latlon,
    float4* __restrict__ pf4, int* __restrict__ cnt64,
    float4* __restrict__ rowvec) {
    const int tid = threadIdx.x;
    if (blockIdx.x >= 16) {
        int b = (blockIdx.x - 16) * 256 + tid;
        float latd = latlon[2 * b];
        float lat = latd * DEG2RAD, lon = latlon[2 * b + 1] * DEG2RAD;
        float cl = cosf(lat);
        rowvec[b] = make_float4(-0.5f * cl * cosf(lon), -0.5f * cl * sinf(lon),
                                -0.5f * sinf(lat), latd);
        return;
    }
    const int lane = tid & 63;
    const int j = blockIdx.x * 4 + (tid >> 6);   // this wave's bin
    int base = 0;
    for (int c0 = 0; c0 < C_; c0 += 64) {
        int c = c0 + lane;
        float latd = centroids[2 * c];
        int bin = (int)floorf((latd + 90.0f) * BINSCALE);
        bin = bin < 0 ? 0 : (bin > 63 ? 63 : bin);
        bool flag = (bin == j);
        unsigned long long m = __ballot(flag);
        if (flag) {
            int dst = base + (int)__popcll(m & ((1ull << lane) - 1ull));
            if (dst < CAP) {
                float lat = latd * DEG2RAD, lon = centroids[2 * c + 1] * DEG2RAD;
                float cl = cosf(lat);
                pf4[j * CAP + dst] = make_float4(cl * cosf(lon), cl * sinf(lon),
                                                 sinf(lat), __int_as_float(c));
            }
        }
        base += (int)__popcll(m);
    }
    int cnt = base < CAP ? base : CAP;
    int cntp = (cnt + 63) & ~63;
    for (int k = cnt + lane; k < cntp; k += 64)
        pf4[j * CAP + k] = make_float4(0.f, 0.f, 0.f, __int_as_float(0));
    if (lane == 0) cnt64[j] = cntp;
}

// 1024 threads (16 waves), one row per block. LDS 48.2 KB -> 2 blocks/CU =
// 32 waves/CU = 100% occupancy (round 9's 256-thread version sat at 37%).
// Pass 1: compulsory coalesced stream -> LDS + softmax denominator S.
// Pass 2: W,T over lat-band bins only; logits gathered from LDS.
__global__ __launch_bounds__(1024, 2) void row_loss_kernel(
    const float* __restrict__ logits, const float4* __restrict__ pf4,
    const int* __restrict__ cnt64, const float4* __restrict__ rowvec,
    float* __restrict__ row_loss) {
    __shared__ float ls[C_];
    __shared__ float red[3][16];
    const int b = blockIdx.x;
    const int tid = threadIdx.x;
    float4 rv = rowvec[b];
    const float nx = rv.x, ny = rv.y, nz = rv.z, latd = rv.w;

    const float4* __restrict__ l4 = (const float4*)(logits + (size_t)b * C_);
    float4* __restrict__ ls4 = (float4*)ls;
    float S = 0.f;
#pragma unroll
    for (int i = 0; i < C_ / 4 / 1024; ++i) {
        int idx = i * 1024 + tid;
        float4 l = l4[idx];
        ls4[idx] = l;
        S += __builtin_amdgcn_exp2f(l.x * LOG2E) +
             __builtin_amdgcn_exp2f(l.y * LOG2E) +
             __builtin_amdgcn_exp2f(l.z * LOG2E) +
             __builtin_amdgcn_exp2f(l.w * LOG2E);
    }
    __syncthreads();

    float W = 0.f, T = 0.f;
    int jlo = (int)floorf((latd - BANDDEG + 90.0f) * BINSCALE);
    int jhi = (int)floorf((latd + BANDDEG + 90.0f) * BINSCALE);
    jlo = jlo < 0 ? 0 : jlo;
    jhi = jhi > 63 ? 63 : jhi;
    for (int j = jlo; j <= jhi; ++j) {
        const int n = cnt64[j];
        const float4* __restrict__ bp = pf4 + j * CAP;
        for (int k = tid; k < n; k += 1024) {
            float4 q = bp[k];
            int col = __float_as_int(q.w);
            float a = fmaf(nx, q.x, fmaf(ny, q.y, fmaf(nz, q.z, 0.5f)));
            float s = __builtin_amdgcn_sqrtf(a);
            float w = __builtin_amdgcn_exp2f(s * fmaf(a, C1, C0));
            float l = ls[col];
            W += w;
            T = fmaf(w, l, T);
        }
    }

    W = wave_red_add(W);
    T = wave_red_add(T);
    S = wave_red_add(S);
    const int lane = tid & 63, wv = tid >> 6;
    if (lane == 0) { red[0][wv] = W; red[1][wv] = T; red[2][wv] = S; }
    __syncthreads();
    if (tid == 0) {
        float Wt = 0.f, Tt = 0.f, St = 0.f;
#pragma unroll
        for (int t = 0; t < 16; ++t) {
            Wt += red[0][t];
            Tt += red[1][t];
            St += red[2][t];
        }
        Wt = fmaxf(Wt, 1e-30f);
        row_loss[b] = logf(St) - Tt / Wt;
    }
}

__global__ __launch_bounds__(256) void final_reduce_kernel(
    const float* __restrict__ row_loss, float* __restrict__ out) {
    float s = 0.f;
    for (int i = threadIdx.x; i < B_; i += 256) s += row_loss[i];
    s = wave_red_add(s);
    __shared__ float red[4];
    const int lane = threadIdx.x & 63, wv = threadIdx.x >> 6;
    if (lane == 0) red[wv] = s;
    __syncthreads();
    if (threadIdx.x == 0)
        out[0] = (red[0] + red[1] + red[2] + red[3]) * (1.0f / B_);
}

extern "C" void kernel_launch(void* const* d_in, const int* in_sizes, int n_in,
                              void* d_out, int out_size, void* d_ws, size_t ws_size,
                              hipStream_t stream) {
    const float* pred_logits = (const float*)d_in[0];  // [B, C] f32
    const float* latlon      = (const float*)d_in[1];  // [B, 2] f32
    const float* centroids   = (const float*)d_in[2];  // [C, 2] f32
    // d_in[3] geocell_indices is unused by the reference.
    float4* pf4     = (float4*)d_ws;               // 64*512 float4 binned centroids
    int*    cnt64   = (int*)(pf4 + NBIN * CAP);    // 64 padded counts
    float4* rowvec  = (float4*)(cnt64 + 64);       // 4096 query vectors
    float*  row_loss = (float*)(rowvec + B_);      // 4096 row losses
    float*  out     = (float*)d_out;

    setup_kernel<<<32, 256, 0, stream>>>(centroids, latlon, pf4, cnt64, rowvec);
    row_loss_kernel<<<B_, 1024, 0, stream>>>(pred_logits, pf4, cnt64, rowvec,
                                             row_loss);
    final_reduce_kernel<<<1, 256, 0, stream>>>(row_loss, out);
}

// Round 11
// 54.920 us; speedup vs baseline: 2.8318x; 2.8318x over previous
//
#include <hip/hip_runtime.h>
#include <math.h>

namespace {
constexpr int B_ = 4096;
constexpr int C_ = 12288;
constexpr int R_ = 2;                    // rows per block
constexpr float DEG2RAD = 0.017453292519943295f;
constexpr float LOG2E = 1.4426950408889634f;
// w = exp(-2R*asin(s)/tau) = exp2(KN2*asin(s)), KN2 = -(2*6371/75)*log2(e)
constexpr float KN2 = -245.10427f;
// asin(s) ~= s*(1 + a/6), a = s^2. Truncation ~1e-5 in the exponent where w
// matters -> invisible. KN2*asin(s) = s*(C0 + C1*a).
constexpr float C0 = KN2;
constexpr float C1 = KN2 / 6.0f;
typedef float f32x4 __attribute__((ext_vector_type(4)));
}

// Per-centroid HALF unit-sphere coords, interleaved per 4-centroid group:
// group g occupies 12 floats: [x0..x3][y0..y3][z0..z3] -> one address stream.
__global__ void centroid_xyz_kernel(const float* __restrict__ centroids,
                                    float* __restrict__ ctq) {
    int c = blockIdx.x * blockDim.x + threadIdx.x;
    if (c >= C_) return;
    float lat = centroids[2 * c] * DEG2RAD;
    float lon = centroids[2 * c + 1] * DEG2RAD;
    float cl = cosf(lat);
    int g = c >> 2, j = c & 3;
    ctq[12 * g + j]     = 0.5f * cl * cosf(lon);
    ctq[12 * g + 4 + j] = 0.5f * cl * sinf(lon);
    ctq[12 * g + 8 + j] = 0.5f * sinf(lat);
}

__device__ __forceinline__ float wave_red_add(float v) {
#pragma unroll
    for (int off = 32; off > 0; off >>= 1) v += __shfl_down(v, off, 64);
    return v;
}

__device__ __forceinline__ void accum_pair(float lv, float xv, float yv, float zv,
                                           float x1, float y1, float z1,
                                           float& W, float& T, float& S) {
    float dx = xv - x1, dy = yv - y1, dz = zv - z1;
    float a = fmaf(dx, dx, fmaf(dy, dy, dz * dz));   // = sin^2(theta/2)
    float s = __builtin_amdgcn_sqrtf(a);             // sin(theta/2)
    float p = fmaf(a, C1, C0);
    float w = __builtin_amdgcn_exp2f(s * p);         // exp(-dist/tau)
    W += w;
    T = fmaf(w, lv, T);
    S += __builtin_amdgcn_exp2f(lv * LOG2E);         // exp(l)
}

// One block per R_ rows; per 4-centroid group: 3 ct dwordx4 (one cached
// stream) + R_ logits dwordx4 (NON-TEMPORAL: read-once 201 MB stream must not
// evict the reused 144 KB ct table from L2).
__global__ __launch_bounds__(256) void row_loss_kernel(
    const float* __restrict__ logits, const float* __restrict__ latlon,
    const float* __restrict__ ctq, float* __restrict__ row_loss) {
    const int b0 = blockIdx.x * R_;

    float x1[R_], y1[R_], z1[R_];
#pragma unroll
    for (int r = 0; r < R_; ++r) {
        float lat = latlon[2 * (b0 + r)] * DEG2RAD;
        float lon = latlon[2 * (b0 + r) + 1] * DEG2RAD;
        float cl = cosf(lat);
        x1[r] = 0.5f * cl * cosf(lon);
        y1[r] = 0.5f * cl * sinf(lon);
        z1[r] = 0.5f * sinf(lat);
    }

    const float4* __restrict__ ct4 = (const float4*)ctq + 3 * (size_t)threadIdx.x;
    const f32x4* __restrict__ L0 =
        (const f32x4*)(logits + (size_t)b0 * C_) + threadIdx.x;
    const f32x4* __restrict__ L1 =
        (const f32x4*)(logits + (size_t)(b0 + 1) * C_) + threadIdx.x;

    float W[R_], T[R_], S[R_];
#pragma unroll
    for (int r = 0; r < R_; ++r) { W[r] = 0.f; T[r] = 0.f; S[r] = 0.f; }

#pragma unroll 2
    for (int i = 0; i < C_ / 4 / 256; ++i) {
        float4 X = ct4[0];
        float4 Y = ct4[1];
        float4 Z = ct4[2];
        f32x4 la = __builtin_nontemporal_load(L0);
        f32x4 lb = __builtin_nontemporal_load(L1);
        accum_pair(la.x, X.x, Y.x, Z.x, x1[0], y1[0], z1[0], W[0], T[0], S[0]);
        accum_pair(la.y, X.y, Y.y, Z.y, x1[0], y1[0], z1[0], W[0], T[0], S[0]);
        accum_pair(la.z, X.z, Y.z, Z.z, x1[0], y1[0], z1[0], W[0], T[0], S[0]);
        accum_pair(la.w, X.w, Y.w, Z.w, x1[0], y1[0], z1[0], W[0], T[0], S[0]);
        accum_pair(lb.x, X.x, Y.x, Z.x, x1[1], y1[1], z1[1], W[1], T[1], S[1]);
        accum_pair(lb.y, X.y, Y.y, Z.y, x1[1], y1[1], z1[1], W[1], T[1], S[1]);
        accum_pair(lb.z, X.z, Y.z, Z.z, x1[1], y1[1], z1[1], W[1], T[1], S[1]);
        accum_pair(lb.w, X.w, Y.w, Z.w, x1[1], y1[1], z1[1], W[1], T[1], S[1]);
        ct4 += 3 * 256;
        L0 += 256;
        L1 += 256;
    }

    __shared__ float red[3][R_][4];
    const int lane = threadIdx.x & 63, wv = threadIdx.x >> 6;
#pragma unroll
    for (int r = 0; r < R_; ++r) {
        float Wr = wave_red_add(W[r]);
        float Tr = wave_red_add(T[r]);
        float Sr = wave_red_add(S[r]);
        if (lane == 0) { red[0][r][wv] = Wr; red[1][r][wv] = Tr; red[2][r][wv] = Sr; }
    }
    __syncthreads();
    if (threadIdx.x < R_) {
        int r = threadIdx.x;
        float Wt = red[0][r][0] + red[0][r][1] + red[0][r][2] + red[0][r][3];
        float Tt = red[1][r][0] + red[1][r][1] + red[1][r][2] + red[1][r][3];
        float St = red[2][r][0] + red[2][r][1] + red[2][r][2] + red[2][r][3];
        Wt = fmaxf(Wt, 1e-30f);
        row_loss[b0 + r] = logf(St) - Tt / Wt;
    }
}

__global__ __launch_bounds__(256) void final_reduce_kernel(
    const float* __restrict__ row_loss, float* __restrict__ out) {
    float s = 0.f;
    for (int i = threadIdx.x; i < B_; i += 256) s += row_loss[i];
    s = wave_red_add(s);
    __shared__ float red[4];
    const int lane = threadIdx.x & 63, wv = threadIdx.x >> 6;
    if (lane == 0) red[wv] = s;
    __syncthreads();
    if (threadIdx.x == 0)
        out[0] = (red[0] + red[1] + red[2] + red[3]) * (1.0f / B_);
}

extern "C" void kernel_launch(void* const* d_in, const int* in_sizes, int n_in,
                              void* d_out, int out_size, void* d_ws, size_t ws_size,
                              hipStream_t stream) {
    const float* pred_logits = (const float*)d_in[0];  // [B, C] f32
    const float* latlon      = (const float*)d_in[1];  // [B, 2] f32
    const float* centroids   = (const float*)d_in[2];  // [C, 2] f32
    // d_in[3] geocell_indices is unused by the reference.
    float* ctq      = (float*)d_ws;      // 3*C floats, interleaved quads
    float* row_loss = ctq + 3 * C_;      // B floats
    float* out      = (float*)d_out;

    centroid_xyz_kernel<<<(C_ + 255) / 256, 256, 0, stream>>>(centroids, ctq);
    row_loss_kernel<<<B_ / R_, 256, 0, stream>>>(pred_logits, latlon, ctq, row_loss);
    final_reduce_kernel<<<1, 256, 0, stream>>>(row_loss, out);
}

// Round 12
// 48.543 us; speedup vs baseline: 3.2038x; 1.1314x over previous
//
#include <hip/hip_runtime.h>
#include <math.h>

namespace {
constexpr int B_ = 4096;
constexpr int C_ = 12288;
constexpr int R_ = 2;                    // rows per block
constexpr int NI = C_ / 4 / 256;         // 12 main-loop iterations
constexpr float DEG2RAD = 0.017453292519943295f;
constexpr float LOG2E = 1.4426950408889634f;
// w = exp(-2R*asin(s)/tau) = exp2(KN2*asin(s)), KN2 = -(2*6371/75)*log2(e)
constexpr float KN2 = -245.10427f;
// asin(s) ~= s*(1 + a/6), a = s^2. Truncation ~1e-5 in the exponent where w
// matters -> invisible. KN2*asin(s) = s*(C0 + C1*a).
constexpr float C0 = KN2;
constexpr float C1 = KN2 / 6.0f;
}

// Per-centroid HALF unit-sphere coords, interleaved per 4-centroid group:
// group g occupies 12 floats: [x0..x3][y0..y3][z0..z3] -> one address stream.
__global__ void centroid_xyz_kernel(const float* __restrict__ centroids,
                                    float* __restrict__ ctq) {
    int c = blockIdx.x * blockDim.x + threadIdx.x;
    if (c >= C_) return;
    float lat = centroids[2 * c] * DEG2RAD;
    float lon = centroids[2 * c + 1] * DEG2RAD;
    float cl = cosf(lat);
    int g = c >> 2, j = c & 3;
    ctq[12 * g + j]     = 0.5f * cl * cosf(lon);
    ctq[12 * g + 4 + j] = 0.5f * cl * sinf(lon);
    ctq[12 * g + 8 + j] = 0.5f * sinf(lat);
}

__device__ __forceinline__ float wave_red_add(float v) {
#pragma unroll
    for (int off = 32; off > 0; off >>= 1) v += __shfl_down(v, off, 64);
    return v;
}

__device__ __forceinline__ void accum_pair(float lv, float xv, float yv, float zv,
                                           float x1, float y1, float z1,
                                           float& W, float& T, float& S) {
    float dx = xv - x1, dy = yv - y1, dz = zv - z1;
    float a = fmaf(dx, dx, fmaf(dy, dy, dz * dz));   // = sin^2(theta/2)
    float s = __builtin_amdgcn_sqrtf(a);             // sin(theta/2)
    float p = fmaf(a, C1, C0);
    float w = __builtin_amdgcn_exp2f(s * p);         // exp(-dist/tau)
    W += w;
    T = fmaf(w, lv, T);
    S += __builtin_amdgcn_exp2f(lv * LOG2E);         // exp(l)
}

// One block per R_ rows. Explicit 1-iteration software pipeline: iteration
// i+1's 5 loads are issued before iteration i's 8 accum_pairs, so each wave
// always has ~1 iteration of latency cover on top of 8-wave TLP.
__global__ __launch_bounds__(256) void row_loss_kernel(
    const float* __restrict__ logits, const float* __restrict__ latlon,
    const float* __restrict__ ctq, float* __restrict__ row_loss) {
    const int b0 = blockIdx.x * R_;

    float x1[R_], y1[R_], z1[R_];
#pragma unroll
    for (int r = 0; r < R_; ++r) {
        float lat = latlon[2 * (b0 + r)] * DEG2RAD;
        float lon = latlon[2 * (b0 + r) + 1] * DEG2RAD;
        float cl = cosf(lat);
        x1[r] = 0.5f * cl * cosf(lon);
        y1[r] = 0.5f * cl * sinf(lon);
        z1[r] = 0.5f * sinf(lat);
    }

    const float4* __restrict__ ct4 = (const float4*)ctq + 3 * (size_t)threadIdx.x;
    const float4* __restrict__ L0 =
        (const float4*)(logits + (size_t)b0 * C_) + threadIdx.x;
    const float4* __restrict__ L1 =
        (const float4*)(logits + (size_t)(b0 + 1) * C_) + threadIdx.x;

    float W[R_], T[R_], S[R_];
#pragma unroll
    for (int r = 0; r < R_; ++r) { W[r] = 0.f; T[r] = 0.f; S[r] = 0.f; }

    float4 X = ct4[0], Y = ct4[1], Z = ct4[2];
    float4 la = *L0, lb = *L1;
#pragma unroll 2
    for (int i = 0; i < NI - 1; ++i) {
        ct4 += 3 * 256;
        L0 += 256;
        L1 += 256;
        float4 Xn = ct4[0], Yn = ct4[1], Zn = ct4[2];
        float4 lan = *L0, lbn = *L1;
        accum_pair(la.x, X.x, Y.x, Z.x, x1[0], y1[0], z1[0], W[0], T[0], S[0]);
        accum_pair(la.y, X.y, Y.y, Z.y, x1[0], y1[0], z1[0], W[0], T[0], S[0]);
        accum_pair(la.z, X.z, Y.z, Z.z, x1[0], y1[0], z1[0], W[0], T[0], S[0]);
        accum_pair(la.w, X.w, Y.w, Z.w, x1[0], y1[0], z1[0], W[0], T[0], S[0]);
        accum_pair(lb.x, X.x, Y.x, Z.x, x1[1], y1[1], z1[1], W[1], T[1], S[1]);
        accum_pair(lb.y, X.y, Y.y, Z.y, x1[1], y1[1], z1[1], W[1], T[1], S[1]);
        accum_pair(lb.z, X.z, Y.z, Z.z, x1[1], y1[1], z1[1], W[1], T[1], S[1]);
        accum_pair(lb.w, X.w, Y.w, Z.w, x1[1], y1[1], z1[1], W[1], T[1], S[1]);
        X = Xn; Y = Yn; Z = Zn;
        la = lan; lb = lbn;
    }
    accum_pair(la.x, X.x, Y.x, Z.x, x1[0], y1[0], z1[0], W[0], T[0], S[0]);
    accum_pair(la.y, X.y, Y.y, Z.y, x1[0], y1[0], z1[0], W[0], T[0], S[0]);
    accum_pair(la.z, X.z, Y.z, Z.z, x1[0], y1[0], z1[0], W[0], T[0], S[0]);
    accum_pair(la.w, X.w, Y.w, Z.w, x1[0], y1[0], z1[0], W[0], T[0], S[0]);
    accum_pair(lb.x, X.x, Y.x, Z.x, x1[1], y1[1], z1[1], W[1], T[1], S[1]);
    accum_pair(lb.y, X.y, Y.y, Z.y, x1[1], y1[1], z1[1], W[1], T[1], S[1]);
    accum_pair(lb.z, X.z, Y.z, Z.z, x1[1], y1[1], z1[1], W[1], T[1], S[1]);
    accum_pair(lb.w, X.w, Y.w, Z.w, x1[1], y1[1], z1[1], W[1], T[1], S[1]);

    __shared__ float red[3][R_][4];
    const int lane = threadIdx.x & 63, wv = threadIdx.x >> 6;
#pragma unroll
    for (int r = 0; r < R_; ++r) {
        float Wr = wave_red_add(W[r]);
        float Tr = wave_red_add(T[r]);
        float Sr = wave_red_add(S[r]);
        if (lane == 0) { red[0][r][wv] = Wr; red[1][r][wv] = Tr; red[2][r][wv] = Sr; }
    }
    __syncthreads();
    if (threadIdx.x < R_) {
        int r = threadIdx.x;
        float Wt = red[0][r][0] + red[0][r][1] + red[0][r][2] + red[0][r][3];
        float Tt = red[1][r][0] + red[1][r][1] + red[1][r][2] + red[1][r][3];
        float St = red[2][r][0] + red[2][r][1] + red[2][r][2] + red[2][r][3];
        Wt = fmaxf(Wt, 1e-30f);
        row_loss[b0 + r] = logf(St) - Tt / Wt;
    }
}

__global__ __launch_bounds__(256) void final_reduce_kernel(
    const float* __restrict__ row_loss, float* __restrict__ out) {
    float s = 0.f;
    for (int i = threadIdx.x; i < B_; i += 256) s += row_loss[i];
    s = wave_red_add(s);
    __shared__ float red[4];
    const int lane = threadIdx.x & 63, wv = threadIdx.x >> 6;
    if (lane == 0) red[wv] = s;
    __syncthreads();
    if (threadIdx.x == 0)
        out[0] = (red[0] + red[1] + red[2] + red[3]) * (1.0f / B_);
}

extern "C" void kernel_launch(void* const* d_in, const int* in_sizes, int n_in,
                              void* d_out, int out_size, void* d_ws, size_t ws_size,
                              hipStream_t stream) {
    const float* pred_logits = (const float*)d_in[0];  // [B, C] f32
    const float* latlon      = (const float*)d_in[1];  // [B, 2] f32
    const float* centroids   = (const float*)d_in[2];  // [C, 2] f32
    // d_in[3] geocell_indices is unused by the reference.
    float* ctq      = (float*)d_ws;      // 3*C floats, interleaved quads
    float* row_loss = ctq + 3 * C_;      // B floats
    float* out      = (float*)d_out;

    centroid_xyz_kernel<<<(C_ + 255) / 256, 256, 0, stream>>>(centroids, ctq);
    row_loss_kernel<<<B_ / R_, 256, 0, stream>>>(pred_logits, latlon, ctq, row_loss);
    final_reduce_kernel<<<1, 256, 0, stream>>>(row_loss, out);
}

// Round 13
// 46.264 us; speedup vs baseline: 3.3617x; 1.0493x over previous
//
#include <hip/hip_runtime.h>
#include <math.h>

namespace {
constexpr int B_ = 4096;
constexpr int C_ = 12288;
constexpr int R_ = 2;                    // rows per block
constexpr float DEG2RAD = 0.017453292519943295f;
constexpr float LOG2E = 1.4426950408889634f;
// w = exp(-2R*asin(s)/tau) = exp2(KN2*asin(s)), KN2 = -(2*6371/75)*log2(e)
constexpr float KN2 = -245.10427f;
// asin(s) ~= s*(1 + a/6), a = s^2. Truncation ~1e-5 in the exponent where w
// matters -> invisible. KN2*asin(s) = s*(C0 + C1*a).
constexpr float C0 = KN2;
constexpr float C1 = KN2 / 6.0f;
typedef float f32x2 __attribute__((ext_vector_type(2)));
}

// Per-centroid HALF unit-sphere coords, interleaved per 4-centroid group:
// group g occupies 12 floats: [x0..x3][y0..y3][z0..z3] -> one address stream.
__global__ void centroid_xyz_kernel(const float* __restrict__ centroids,
                                    float* __restrict__ ctq) {
    int c = blockIdx.x * blockDim.x + threadIdx.x;
    if (c >= C_) return;
    float lat = centroids[2 * c] * DEG2RAD;
    float lon = centroids[2 * c + 1] * DEG2RAD;
    float cl = cosf(lat);
    int g = c >> 2, j = c & 3;
    ctq[12 * g + j]     = 0.5f * cl * cosf(lon);
    ctq[12 * g + 4 + j] = 0.5f * cl * sinf(lon);
    ctq[12 * g + 8 + j] = 0.5f * sinf(lat);
}

__device__ __forceinline__ float wave_red_add(float v) {
#pragma unroll
    for (int off = 32; off > 0; off >>= 1) v += __shfl_down(v, off, 64);
    return v;
}

// Process TWO pairs per call as f32x2 so the regular VALU ops pack into
// VOP3P v_pk_fma_f32/v_pk_mul_f32 (2 fp32/lane/inst, full rate on CDNA4).
// sqrt/exp2 have no packed form and stay scalar.
__device__ __forceinline__ void accum_pair2(f32x2 l2, f32x2 x2, f32x2 y2,
                                            f32x2 z2, float x1, float y1,
                                            float z1, f32x2& W, f32x2& T,
                                            f32x2& S) {
    f32x2 dx = x2 - x1, dy = y2 - y1, dz = z2 - z1;
    f32x2 a = dx * dx + dy * dy + dz * dz;           // = sin^2(theta/2), packed
    f32x2 s;
    s.x = __builtin_amdgcn_sqrtf(a.x);
    s.y = __builtin_amdgcn_sqrtf(a.y);
    f32x2 p = a * C1 + C0;                            // packed fma
    f32x2 e = s * p;
    f32x2 w;
    w.x = __builtin_amdgcn_exp2f(e.x);
    w.y = __builtin_amdgcn_exp2f(e.y);
    W += w;                                           // packed add
    T += w * l2;                                      // packed fma
    f32x2 le = l2 * LOG2E;
    f32x2 el;
    el.x = __builtin_amdgcn_exp2f(le.x);
    el.y = __builtin_amdgcn_exp2f(le.y);
    S += el;                                          // packed add
}

// One block per R_ rows; per 4-centroid group: 3 ct dwordx4 (one stream) +
// R_ logits dwordx4; math runs 2 pairs/lane packed.
__global__ __launch_bounds__(256) void row_loss_kernel(
    const float* __restrict__ logits, const float* __restrict__ latlon,
    const float* __restrict__ ctq, float* __restrict__ row_loss) {
    const int b0 = blockIdx.x * R_;

    float x1[R_], y1[R_], z1[R_];
#pragma unroll
    for (int r = 0; r < R_; ++r) {
        float lat = latlon[2 * (b0 + r)] * DEG2RAD;
        float lon = latlon[2 * (b0 + r) + 1] * DEG2RAD;
        float cl = cosf(lat);
        x1[r] = 0.5f * cl * cosf(lon);
        y1[r] = 0.5f * cl * sinf(lon);
        z1[r] = 0.5f * sinf(lat);
    }

    const float4* __restrict__ ct4 = (const float4*)ctq + 3 * (size_t)threadIdx.x;
    const float4* __restrict__ L0 =
        (const float4*)(logits + (size_t)b0 * C_) + threadIdx.x;
    const float4* __restrict__ L1 =
        (const float4*)(logits + (size_t)(b0 + 1) * C_) + threadIdx.x;

    f32x2 W[R_], T[R_], S[R_];
#pragma unroll
    for (int r = 0; r < R_; ++r) {
        W[r] = (f32x2)(0.f);
        T[r] = (f32x2)(0.f);
        S[r] = (f32x2)(0.f);
    }

#pragma unroll 2
    for (int i = 0; i < C_ / 4 / 256; ++i) {
        float4 X = ct4[0];
        float4 Y = ct4[1];
        float4 Z = ct4[2];
        float4 la = *L0;
        float4 lb = *L1;
        f32x2 X0 = {X.x, X.y}, X1v = {X.z, X.w};
        f32x2 Y0 = {Y.x, Y.y}, Y1v = {Y.z, Y.w};
        f32x2 Z0 = {Z.x, Z.y}, Z1v = {Z.z, Z.w};
        f32x2 la0 = {la.x, la.y}, la1 = {la.z, la.w};
        f32x2 lb0 = {lb.x, lb.y}, lb1 = {lb.z, lb.w};
        accum_pair2(la0, X0, Y0, Z0, x1[0], y1[0], z1[0], W[0], T[0], S[0]);
        accum_pair2(la1, X1v, Y1v, Z1v, x1[0], y1[0], z1[0], W[0], T[0], S[0]);
        accum_pair2(lb0, X0, Y0, Z0, x1[1], y1[1], z1[1], W[1], T[1], S[1]);
        accum_pair2(lb1, X1v, Y1v, Z1v, x1[1], y1[1], z1[1], W[1], T[1], S[1]);
        ct4 += 3 * 256;
        L0 += 256;
        L1 += 256;
    }

    __shared__ float red[3][R_][4];
    const int lane = threadIdx.x & 63, wv = threadIdx.x >> 6;
#pragma unroll
    for (int r = 0; r < R_; ++r) {
        float Wr = wave_red_add(W[r].x + W[r].y);
        float Tr = wave_red_add(T[r].x + T[r].y);
        float Sr = wave_red_add(S[r].x + S[r].y);
        if (lane == 0) { red[0][r][wv] = Wr; red[1][r][wv] = Tr; red[2][r][wv] = Sr; }
    }
    __syncthreads();
    if (threadIdx.x < R_) {
        int r = threadIdx.x;
        float Wt = red[0][r][0] + red[0][r][1] + red[0][r][2] + red[0][r][3];
        float Tt = red[1][r][0] + red[1][r][1] + red[1][r][2] + red[1][r][3];
        float St = red[2][r][0] + red[2][r][1] + red[2][r][2] + red[2][r][3];
        Wt = fmaxf(Wt, 1e-30f);
        row_loss[b0 + r] = logf(St) - Tt / Wt;
    }
}

__global__ __launch_bounds__(256) void final_reduce_kernel(
    const float* __restrict__ row_loss, float* __restrict__ out) {
    float s = 0.f;
    for (int i = threadIdx.x; i < B_; i += 256) s += row_loss[i];
    s = wave_red_add(s);
    __shared__ float red[4];
    const int lane = threadIdx.x & 63, wv = threadIdx.x >> 6;
    if (lane == 0) red[wv] = s;
    __syncthreads();
    if (threadIdx.x == 0)
        out[0] = (red[0] + red[1] + red[2] + red[3]) * (1.0f / B_);
}

extern "C" void kernel_launch(void* const* d_in, const int* in_sizes, int n_in,
                              void* d_out, int out_size, void* d_ws, size_t ws_size,
                              hipStream_t stream) {
    const float* pred_logits = (const float*)d_in[0];  // [B, C] f32
    const float* latlon      = (const float*)d_in[1];  // [B, 2] f32
    const float* centroids   = (const float*)d_in[2];  // [C, 2] f32
    // d_in[3] geocell_indices is unused by the reference.
    float* ctq      = (float*)d_ws;      // 3*C floats, interleaved quads
    float* row_loss = ctq + 3 * C_;      // B floats
    float* out      = (float*)d_out;

    centroid_xyz_kernel<<<(C_ + 255) / 256, 256, 0, stream>>>(centroids, ctq);
    row_loss_kernel<<<B_ / R_, 256, 0, stream>>>(pred_logits, latlon, ctq, row_loss);
    final_reduce_kernel<<<1, 256, 0, stream>>>(row_loss, out);
}